// Round 1
// baseline (416.055 us; speedup 1.0000x reference)
//
#include <hip/hip_runtime.h>

typedef unsigned short u16;
typedef u16 u16x8 __attribute__((ext_vector_type(8)));
typedef __bf16 bf16x8 __attribute__((ext_vector_type(8)));
typedef float f32x4 __attribute__((ext_vector_type(4)));

#define NPIX 100352   // 32*56*56
#define KTOT 2304     // 3*3*256

static __device__ __forceinline__ u16 f2bf(float f) {
  // round-to-nearest-even fp32 -> bf16 (inputs are finite normals)
  unsigned u = __float_as_uint(f);
  return (u16)((u + 0x7fffu + ((u >> 16) & 1u)) >> 16);
}

static __device__ __forceinline__ bf16x8 as_bf(u16x8 v) {
  union { u16x8 u; bf16x8 b; } t; t.u = v; return t.b;
}

// ---------- scale[f] = sum_k |w[k][f]| (divide by 2304 later) ----------
__global__ void scale_accum_k(const float* __restrict__ w, float* __restrict__ scale) {
  const int t = threadIdx.x;
  const long b = blockIdx.x;          // 0..8, each covers 256 k-rows
  const float* p = w + b * 256 * 256 + t;
  float acc = 0.f;
#pragma unroll 8
  for (int e = 0; e < 256; ++e) acc += fabsf(p[(long)e * 256]);
  atomicAdd(&scale[t], acc);
}

// ---------- wp[f][k] = bf16( scale[f]/2304 * sign(w[k][f]) * mask[k][f] ) ----------
__global__ void pack_w_k(const float* __restrict__ w, const float* __restrict__ mask,
                         const float* __restrict__ ssum, u16* __restrict__ wp) {
  __shared__ u16 t[128][33];          // transpose tile, padded
  const int k0 = blockIdx.x * 32;     // 72
  const int f0 = blockIdx.y * 128;    // 2
  const int tid = threadIdx.x;
#pragma unroll
  for (int i = 0; i < 16; ++i) {
    int idx = tid + i * 256;          // 0..4095 over 32k x 128f
    int kk = idx >> 7;
    int ff = idx & 127;
    long g = (long)(k0 + kk) * 256 + f0 + ff;   // coalesced over ff
    float wv = w[g];
    float mv = mask[g];
    float sc = ssum[f0 + ff] * (1.0f / 2304.0f);
    float sg = (wv > 0.f) ? 1.f : ((wv < 0.f) ? -1.f : 0.f);
    t[ff][kk] = f2bf(sc * sg * mv);
  }
  __syncthreads();
#pragma unroll
  for (int i = 0; i < 8; ++i) {
    int idx = tid + i * 256;          // 0..2047 over 128 rows x 16 dwords
    int row = idx >> 4;
    int c = idx & 15;
    unsigned v = (unsigned)t[row][2 * c] | ((unsigned)t[row][2 * c + 1] << 16);
    *(unsigned*)(wp + (long)(f0 + row) * KTOT + k0 + 2 * c) = v;
  }
}

// ---------- x fp32 -> bf16 (fast path precompute) ----------
__global__ void cvt_x_k(const float* __restrict__ x, u16* __restrict__ xb) {
  const long i = ((long)blockIdx.x * 256 + threadIdx.x) * 8;
  float4 a = *(const float4*)(x + i);
  float4 b = *(const float4*)(x + i + 4);
  u16x8 r;
  r[0] = f2bf(a.x); r[1] = f2bf(a.y); r[2] = f2bf(a.z); r[3] = f2bf(a.w);
  r[4] = f2bf(b.x); r[5] = f2bf(b.y); r[6] = f2bf(b.z); r[7] = f2bf(b.w);
  *(u16x8*)(xb + i) = r;
}

// ---------- implicit-GEMM conv: C[M=100352, N=256] = A[M,K=2304] * B^T ----------
// 128x128 block tile, BK=32, 4 waves each 64x64 (4x4 MFMA 16x16x32 bf16).
template <bool XB>
__global__ __launch_bounds__(256) void conv_gemm_k(
    const float* __restrict__ x, const u16* __restrict__ xb,
    const u16* __restrict__ wp, float* __restrict__ out) {
  __shared__ u16 As[128 * 40];   // [m][k], pad 32->40 (conflict-free b128)
  __shared__ u16 Bs[128 * 40];   // [n][k]

  const int tid = threadIdx.x;
  const int m0 = blockIdx.x * 128;
  const int n0 = blockIdx.y * 128;

  // staging map: chunk (row, cc) of 8 elems; thread covers rows r0 and r0+64
  const int cc = tid & 3;
  const int r0 = tid >> 2;            // 0..63
  const int gm0 = m0 + r0;
  const int gm1 = gm0 + 64;
  const int pix0 = gm0 % 3136, oh0 = pix0 / 56, ow0 = pix0 % 56;
  const int pix1 = gm1 % 3136, oh1 = pix1 / 56, ow1 = pix1 % 56;

  const int lane = tid & 63;
  const int wv = tid >> 6;
  const int wm = wv & 1, wn = wv >> 1;
  const int lm = lane & 15, kq = lane >> 4;
  const int aoff = (wm * 64 + lm) * 40 + kq * 8;  // A-frag: A[m=lane&15][k=quad*8+j]
  const int boff = (wn * 64 + lm) * 40 + kq * 8;

  u16* as0 = As + r0 * 40 + cc * 8;
  u16* as1 = As + (r0 + 64) * 40 + cc * 8;
  u16* bs0 = Bs + r0 * 40 + cc * 8;
  u16* bs1 = Bs + (r0 + 64) * 40 + cc * 8;

  const u16* wr0 = wp + (long)(n0 + r0) * KTOT + cc * 8;
  const u16* wr1 = wr0 + (long)64 * KTOT;

  f32x4 acc[4][4] = {};

  for (int khw = 0; khw < 9; ++khw) {
    const int dh = khw / 3 - 1;
    const int dw = khw % 3 - 1;
    const bool v0 = ((unsigned)(oh0 + dh) < 56u) && ((unsigned)(ow0 + dw) < 56u);
    const bool v1 = ((unsigned)(oh1 + dh) < 56u) && ((unsigned)(ow1 + dw) < 56u);
    const long p0 = ((long)gm0 + dh * 56 + dw) * 256 + cc * 8;  // halo pixel base
    const long p1 = ((long)gm1 + dh * 56 + dw) * 256 + cc * 8;
    const u16* wk0 = wr0 + khw * 256;
    const u16* wk1 = wr1 + khw * 256;

    for (int ct = 0; ct < 8; ++ct) {
      const int ci0 = ct * 32;
      u16x8 a0 = {0, 0, 0, 0, 0, 0, 0, 0};
      u16x8 a1 = {0, 0, 0, 0, 0, 0, 0, 0};
      if (XB) {
        if (v0) a0 = *(const u16x8*)(xb + p0 + ci0);
        if (v1) a1 = *(const u16x8*)(xb + p1 + ci0);
      } else {
        float4 l0 = make_float4(0, 0, 0, 0), h0 = make_float4(0, 0, 0, 0);
        float4 l1 = make_float4(0, 0, 0, 0), h1 = make_float4(0, 0, 0, 0);
        if (v0) { l0 = *(const float4*)(x + p0 + ci0); h0 = *(const float4*)(x + p0 + ci0 + 4); }
        if (v1) { l1 = *(const float4*)(x + p1 + ci0); h1 = *(const float4*)(x + p1 + ci0 + 4); }
        a0[0] = f2bf(l0.x); a0[1] = f2bf(l0.y); a0[2] = f2bf(l0.z); a0[3] = f2bf(l0.w);
        a0[4] = f2bf(h0.x); a0[5] = f2bf(h0.y); a0[6] = f2bf(h0.z); a0[7] = f2bf(h0.w);
        a1[0] = f2bf(l1.x); a1[1] = f2bf(l1.y); a1[2] = f2bf(l1.z); a1[3] = f2bf(l1.w);
        a1[4] = f2bf(h1.x); a1[5] = f2bf(h1.y); a1[6] = f2bf(h1.z); a1[7] = f2bf(h1.w);
      }
      u16x8 b0 = *(const u16x8*)(wk0 + ci0);
      u16x8 b1 = *(const u16x8*)(wk1 + ci0);

      __syncthreads();   // prev-iter LDS reads done
      *(u16x8*)as0 = a0;
      *(u16x8*)as1 = a1;
      *(u16x8*)bs0 = b0;
      *(u16x8*)bs1 = b1;
      __syncthreads();   // staging visible

      bf16x8 av[4], bv[4];
#pragma unroll
      for (int i = 0; i < 4; ++i) av[i] = *(const bf16x8*)(As + aoff + i * 640);
#pragma unroll
      for (int i = 0; i < 4; ++i) bv[i] = *(const bf16x8*)(Bs + boff + i * 640);
#pragma unroll
      for (int mi = 0; mi < 4; ++mi) {
#pragma unroll
        for (int ni = 0; ni < 4; ++ni) {
          acc[mi][ni] = __builtin_amdgcn_mfma_f32_16x16x32_bf16(av[mi], bv[ni], acc[mi][ni], 0, 0, 0);
        }
      }
    }
  }

  // epilogue: D col = lane&15 (n), row = quad*4 + reg (m)
  float* op = out + (long)(m0 + wm * 64 + kq * 4) * 256 + n0 + wn * 64 + lm;
#pragma unroll
  for (int mi = 0; mi < 4; ++mi) {
#pragma unroll
    for (int ni = 0; ni < 4; ++ni) {
      float* p = op + (long)mi * 16 * 256 + ni * 16;
      f32x4 v = acc[mi][ni];
      p[0] = v[0];
      p[256] = v[1];
      p[512] = v[2];
      p[768] = v[3];
    }
  }
}

extern "C" void kernel_launch(void* const* d_in, const int* in_sizes, int n_in,
                              void* d_out, int out_size, void* d_ws, size_t ws_size,
                              hipStream_t stream) {
  const float* x = (const float*)d_in[0];
  const float* w = (const float*)d_in[1];
  const float* mask = (const float*)d_in[2];
  float* out = (float*)d_out;

  float* scale = (float*)d_ws;                              // 1024 B (+64 B zero pad)
  u16* wp = (u16*)((char*)d_ws + 1088);                     // 1,179,648 B  [f][k] bf16
  u16* xb = (u16*)((char*)d_ws + 1088 + 1179648);           // 51,380,224 B x as bf16
  const size_t need = 1088 + 1179648 + (size_t)NPIX * 256 * 2;

  hipMemsetAsync(d_ws, 0, 1088, stream);
  scale_accum_k<<<9, 256, 0, stream>>>(w, scale);
  pack_w_k<<<dim3(72, 2), 256, 0, stream>>>(w, mask, scale, wp);
  if (ws_size >= need) {
    cvt_x_k<<<NPIX * 256 / (256 * 8), 256, 0, stream>>>(x, xb);
    conv_gemm_k<true><<<dim3(784, 2), 256, 0, stream>>>(x, xb, wp, out);
  } else {
    conv_gemm_k<false><<<dim3(784, 2), 256, 0, stream>>>(x, xb, wp, out);
  }
}

// Round 2
// 387.525 us; speedup vs baseline: 1.0736x; 1.0736x over previous
//
#include <hip/hip_runtime.h>

typedef unsigned short u16;
typedef u16 u16x8 __attribute__((ext_vector_type(8)));
typedef __bf16 bf16x8 __attribute__((ext_vector_type(8)));
typedef float f32x4 __attribute__((ext_vector_type(4)));

#define NPIX 100352           // 32*56*56
#define KTOT 2304             // 3*3*256
#define IMG_PAD (58 * 58 * 256)

static __device__ __forceinline__ u16 f2bf(float f) {
  unsigned u = __float_as_uint(f);
  return (u16)((u + 0x7fffu + ((u >> 16) & 1u)) >> 16);
}

static __device__ __forceinline__ void gld_lds16(const u16* g, u16* l) {
  __builtin_amdgcn_global_load_lds(
      (const __attribute__((address_space(1))) void*)g,
      (__attribute__((address_space(3))) void*)l, 16, 0, 0);
}

// ---------- scale[f] = sum_k |w[k][f]| ----------
__global__ void scale_accum_k(const float* __restrict__ w, float* __restrict__ scale) {
  const int t = threadIdx.x;
  const float* p = w + (long)blockIdx.x * 64 * 256 + t;
  float acc = 0.f;
#pragma unroll
  for (int e = 0; e < 64; ++e) acc += fabsf(p[(long)e * 256]);
  atomicAdd(&scale[t], acc);
}

// ---------- wp[f][k] = bf16( scale[f]/2304 * sign(w[k][f]) * mask[k][f] ) ----------
__global__ void pack_w_k(const float* __restrict__ w, const float* __restrict__ mask,
                         const float* __restrict__ ssum, u16* __restrict__ wp) {
  __shared__ u16 t[128][33];
  const int k0 = blockIdx.x * 32;
  const int f0 = blockIdx.y * 128;
  const int tid = threadIdx.x;
#pragma unroll
  for (int i = 0; i < 16; ++i) {
    int idx = tid + i * 256;
    int kk = idx >> 7;
    int ff = idx & 127;
    long g = (long)(k0 + kk) * 256 + f0 + ff;
    float wv = w[g];
    float mv = mask[g];
    float sc = ssum[f0 + ff] * (1.0f / 2304.0f);
    float sg = (wv > 0.f) ? 1.f : ((wv < 0.f) ? -1.f : 0.f);
    t[ff][kk] = f2bf(sc * sg * mv);
  }
  __syncthreads();
#pragma unroll
  for (int i = 0; i < 8; ++i) {
    int idx = tid + i * 256;
    int row = idx >> 4;
    int c = idx & 15;
    unsigned v = (unsigned)t[row][2 * c] | ((unsigned)t[row][2 * c + 1] << 16);
    *(unsigned*)(wp + (long)(f0 + row) * KTOT + k0 + 2 * c) = v;
  }
}

// ---------- x fp32 -> bf16 into zero-bordered padded layout [32][58][58][256] ----------
__global__ void fill_xpad_k(const float* __restrict__ x, u16* __restrict__ xp) {
  const int tid = threadIdx.x;
  const int pix = blockIdx.x * 8 + (tid >> 5);
  const int c0 = (tid & 31) * 8;
  const int img = pix / 3136;
  const int r = pix % 3136;
  const int oh = r / 56, ow = r % 56;
  const float* s = x + (long)pix * 256 + c0;
  float4 a = *(const float4*)s;
  float4 b = *(const float4*)(s + 4);
  u16x8 v;
  v[0] = f2bf(a.x); v[1] = f2bf(a.y); v[2] = f2bf(a.z); v[3] = f2bf(a.w);
  v[4] = f2bf(b.x); v[5] = f2bf(b.y); v[6] = f2bf(b.z); v[7] = f2bf(b.w);
  *(u16x8*)(xp + (long)img * IMG_PAD + ((oh + 1) * 58 + ow + 1) * 256 + c0) = v;
}

// ---------- implicit-GEMM conv, m97 structure: global_load_lds + swizzled LDS ----------
// C[M=100352,N=256] = A[M,K=2304] * B^T; 128x128 tile, BK=32, 4 waves, 4x4 MFMA 16x16x32.
__global__ __launch_bounds__(256) void conv_gemm2_k(
    const u16* __restrict__ xpad, const u16* __restrict__ wp, float* __restrict__ out) {
  __shared__ u16 As[128 * 32];   // [row][32k], 64 B/row, XOR-swizzled chunks
  __shared__ u16 Bs[128 * 32];

  const int tid = threadIdx.x;
  const int lane = tid & 63;
  const int wv = tid >> 6;
  const int m0 = blockIdx.x * 128;
  const int n0 = blockIdx.y * 128;

  // staging lane map: row = wv*32 + j*16 + (lane>>2); slot = lane&3 holds global
  // chunk cg = (lane&3) ^ (row&3)  (swizzle so frag reads are conflict-free)
  const int srow = lane >> 2;
  const int cg = (lane & 3) ^ (srow & 3);
  const int r0 = wv * 32 + srow;
  const int r1 = r0 + 16;

  const int gm0 = m0 + r0, gm1 = m0 + r1;
  const int i0 = gm0 / 3136, q0 = gm0 % 3136;
  const int i1 = gm1 / 3136, q1 = gm1 % 3136;
  const u16* ap0 = xpad + (long)i0 * IMG_PAD + ((q0 / 56 + 1) * 58 + (q0 % 56) + 1) * 256 + cg * 8;
  const u16* ap1 = xpad + (long)i1 * IMG_PAD + ((q1 / 56 + 1) * 58 + (q1 % 56) + 1) * 256 + cg * 8;
  const u16* bp0 = wp + (long)(n0 + r0) * KTOT + cg * 8;
  const u16* bp1 = wp + (long)(n0 + r1) * KTOT + cg * 8;

  u16* asw0 = As + wv * 1024;        // wave-uniform LDS DMA bases
  u16* asw1 = As + wv * 1024 + 512;
  u16* bsw0 = Bs + wv * 1024;
  u16* bsw1 = Bs + wv * 1024 + 512;

  const int wm = wv & 1, wn = wv >> 1;
  const int lm = lane & 15, kq = lane >> 4;
  const int aoff = (wm * 64 + lm) * 32 + (kq ^ (lm & 3)) * 8;
  const int boff = (wn * 64 + lm) * 32 + (kq ^ (lm & 3)) * 8;

  f32x4 acc[4][4] = {};

  for (int khw = 0; khw < 9; ++khw) {
    const int dh = khw / 3 - 1, dw = khw % 3 - 1;
    const int d = (dh * 58 + dw) * 256;
    const u16* a0 = ap0 + d;
    const u16* a1 = ap1 + d;
    const u16* b0 = bp0 + khw * 256;
    const u16* b1 = bp1 + khw * 256;
#pragma unroll
    for (int ct = 0; ct < 8; ++ct) {
      gld_lds16(a0 + ct * 32, asw0);
      gld_lds16(a1 + ct * 32, asw1);
      gld_lds16(b0 + ct * 32, bsw0);
      gld_lds16(b1 + ct * 32, bsw1);
      __syncthreads();   // drains vmcnt -> DMA visible
      bf16x8 av[4], bv[4];
#pragma unroll
      for (int i = 0; i < 4; ++i) av[i] = *(const bf16x8*)(As + aoff + i * 512);
#pragma unroll
      for (int i = 0; i < 4; ++i) bv[i] = *(const bf16x8*)(Bs + boff + i * 512);
#pragma unroll
      for (int mi = 0; mi < 4; ++mi)
#pragma unroll
        for (int ni = 0; ni < 4; ++ni)
          acc[mi][ni] = __builtin_amdgcn_mfma_f32_16x16x32_bf16(av[mi], bv[ni], acc[mi][ni], 0, 0, 0);
      __syncthreads();   // frag reads done before next DMA overwrites
    }
  }

  // D: col = lane&15 (n), row = quad*4 + reg (m)
  float* op = out + (long)(m0 + wm * 64 + kq * 4) * 256 + n0 + wn * 64 + lm;
#pragma unroll
  for (int mi = 0; mi < 4; ++mi) {
#pragma unroll
    for (int ni = 0; ni < 4; ++ni) {
      float* p = op + (long)mi * 16 * 256 + ni * 16;
      f32x4 v = acc[mi][ni];
      p[0] = v[0];
      p[256] = v[1];
      p[512] = v[2];
      p[768] = v[3];
    }
  }
}

// ---------- fallback (round-1 verified path) if ws too small for xpad ----------
__global__ __launch_bounds__(256) void conv_gemm_fb_k(
    const float* __restrict__ x, const u16* __restrict__ wp, float* __restrict__ out) {
  __shared__ u16 As[128 * 40];
  __shared__ u16 Bs[128 * 40];
  const int tid = threadIdx.x;
  const int m0 = blockIdx.x * 128;
  const int n0 = blockIdx.y * 128;
  const int cc = tid & 3;
  const int r0 = tid >> 2;
  const int gm0 = m0 + r0;
  const int gm1 = gm0 + 64;
  const int pix0 = gm0 % 3136, oh0 = pix0 / 56, ow0 = pix0 % 56;
  const int pix1 = gm1 % 3136, oh1 = pix1 / 56, ow1 = pix1 % 56;
  const int lane = tid & 63;
  const int wv = tid >> 6;
  const int wm = wv & 1, wn = wv >> 1;
  const int lm = lane & 15, kq = lane >> 4;
  const int aoff = (wm * 64 + lm) * 40 + kq * 8;
  const int boff = (wn * 64 + lm) * 40 + kq * 8;
  u16* as0 = As + r0 * 40 + cc * 8;
  u16* as1 = As + (r0 + 64) * 40 + cc * 8;
  u16* bs0 = Bs + r0 * 40 + cc * 8;
  u16* bs1 = Bs + (r0 + 64) * 40 + cc * 8;
  const u16* wr0 = wp + (long)(n0 + r0) * KTOT + cc * 8;
  const u16* wr1 = wr0 + (long)64 * KTOT;
  f32x4 acc[4][4] = {};
  for (int khw = 0; khw < 9; ++khw) {
    const int dh = khw / 3 - 1;
    const int dw = khw % 3 - 1;
    const bool v0 = ((unsigned)(oh0 + dh) < 56u) && ((unsigned)(ow0 + dw) < 56u);
    const bool v1 = ((unsigned)(oh1 + dh) < 56u) && ((unsigned)(ow1 + dw) < 56u);
    const long p0 = ((long)gm0 + dh * 56 + dw) * 256 + cc * 8;
    const long p1 = ((long)gm1 + dh * 56 + dw) * 256 + cc * 8;
    const u16* wk0 = wr0 + khw * 256;
    const u16* wk1 = wr1 + khw * 256;
    for (int ct = 0; ct < 8; ++ct) {
      const int ci0 = ct * 32;
      u16x8 a0 = {0,0,0,0,0,0,0,0}, a1 = {0,0,0,0,0,0,0,0};
      float4 l0 = make_float4(0,0,0,0), h0 = make_float4(0,0,0,0);
      float4 l1 = make_float4(0,0,0,0), h1 = make_float4(0,0,0,0);
      if (v0) { l0 = *(const float4*)(x + p0 + ci0); h0 = *(const float4*)(x + p0 + ci0 + 4); }
      if (v1) { l1 = *(const float4*)(x + p1 + ci0); h1 = *(const float4*)(x + p1 + ci0 + 4); }
      a0[0]=f2bf(l0.x); a0[1]=f2bf(l0.y); a0[2]=f2bf(l0.z); a0[3]=f2bf(l0.w);
      a0[4]=f2bf(h0.x); a0[5]=f2bf(h0.y); a0[6]=f2bf(h0.z); a0[7]=f2bf(h0.w);
      a1[0]=f2bf(l1.x); a1[1]=f2bf(l1.y); a1[2]=f2bf(l1.z); a1[3]=f2bf(l1.w);
      a1[4]=f2bf(h1.x); a1[5]=f2bf(h1.y); a1[6]=f2bf(h1.z); a1[7]=f2bf(h1.w);
      u16x8 b0 = *(const u16x8*)(wk0 + ci0);
      u16x8 b1 = *(const u16x8*)(wk1 + ci0);
      __syncthreads();
      *(u16x8*)as0 = a0; *(u16x8*)as1 = a1;
      *(u16x8*)bs0 = b0; *(u16x8*)bs1 = b1;
      __syncthreads();
      bf16x8 av[4], bv[4];
#pragma unroll
      for (int i = 0; i < 4; ++i) av[i] = *(const bf16x8*)(As + aoff + i * 640);
#pragma unroll
      for (int i = 0; i < 4; ++i) bv[i] = *(const bf16x8*)(Bs + boff + i * 640);
#pragma unroll
      for (int mi = 0; mi < 4; ++mi)
#pragma unroll
        for (int ni = 0; ni < 4; ++ni)
          acc[mi][ni] = __builtin_amdgcn_mfma_f32_16x16x32_bf16(av[mi], bv[ni], acc[mi][ni], 0, 0, 0);
    }
  }
  float* op = out + (long)(m0 + wm * 64 + kq * 4) * 256 + n0 + wn * 64 + lm;
#pragma unroll
  for (int mi = 0; mi < 4; ++mi)
#pragma unroll
    for (int ni = 0; ni < 4; ++ni) {
      float* p = op + (long)mi * 16 * 256 + ni * 16;
      f32x4 v = acc[mi][ni];
      p[0] = v[0]; p[256] = v[1]; p[512] = v[2]; p[768] = v[3];
    }
}

extern "C" void kernel_launch(void* const* d_in, const int* in_sizes, int n_in,
                              void* d_out, int out_size, void* d_ws, size_t ws_size,
                              hipStream_t stream) {
  const float* x = (const float*)d_in[0];
  const float* w = (const float*)d_in[1];
  const float* mask = (const float*)d_in[2];
  float* out = (float*)d_out;

  float* scale = (float*)d_ws;                       // 1024 B + pad
  u16* wp = (u16*)((char*)d_ws + 1088);              // 1,179,648 B  [f][k] bf16
  u16* xpad = (u16*)((char*)d_ws + 1088 + 1179648);  // 55,115,776 B padded bf16 x
  const size_t xpad_bytes = (size_t)32 * IMG_PAD * 2;
  const size_t need = 1088 + 1179648 + xpad_bytes;

  hipMemsetAsync(d_ws, 0, 1088, stream);
  scale_accum_k<<<36, 256, 0, stream>>>(w, scale);
  pack_w_k<<<dim3(72, 2), 256, 0, stream>>>(w, mask, scale, wp);
  if (ws_size >= need) {
    hipMemsetAsync(xpad, 0, xpad_bytes, stream);
    fill_xpad_k<<<NPIX / 8, 256, 0, stream>>>(x, xpad);
    conv_gemm2_k<<<dim3(784, 2), 256, 0, stream>>>(xpad, wp, out);
  } else {
    conv_gemm_fb_k<<<dim3(784, 2), 256, 0, stream>>>(x, wp, out);
  }
}